// Round 4
// baseline (459.879 us; speedup 1.0000x reference)
//
#include <hip/hip_runtime.h>
#include <hip/hip_bf16.h>
#include <stdint.h>
#include <stddef.h>

// ---------------------------------------------------------------------------
// MoE MLP (no inter-GEMM nonlinearity). Inputs/outputs FP32; internal GEMMs
// bf16 MFMA. MT_e = (W1_e @ W2_e)^T precomputed once.
// R4: ATOMIC-FREE output. Tokens grouped by unordered expert pair {ea,eb}
// (28 pairs). gemm_pair runs K over M_ea (accA) then M_eb (accB) and does a
// plain store out[tok] = wa*accA + wb*accB — each out element written exactly
// once. R0-R3 evidence: gemm_moe stuck at 115-131us across 3 staging
// structures; constant = 16.8M device-scope atomics (WRITE_SIZE 64MB = 2x
// out size every round). Also: out-memset removed; losses_kernel
// wave-parallelized (was 1-thread serial global-load loop).
// ---------------------------------------------------------------------------

typedef unsigned short ushort_t;                                   // bf16 bits
typedef __attribute__((ext_vector_type(8))) short short8;          // MFMA A/B frag
typedef __attribute__((ext_vector_type(4))) float floatx4;         // MFMA C/D frag

#define T_TOK 8192
#define NE    8
#define DD    1024
#define FF    2048
#define W1ROW (NE * FF)     // 16384
#define NPAIR 28
#define SBMAX 96            // >= 28 + 8192/128 = 92, multiple of 8

#define BM 128
#define BN 128
#define BK 64

// pair id for ea<eb: compact 0..27
#define PIDX(ea, eb) ((ea) * (15 - (ea)) / 2 + (eb) - (ea) - 1)

typedef const __attribute__((address_space(1))) unsigned int gas_u32;
typedef __attribute__((address_space(3)))       unsigned int las_u32;
// async global->LDS, 16B/lane, LDS dest = wave-uniform base + lane*16
#define GLOAD16(gp, lp) \
  __builtin_amdgcn_global_load_lds((gas_u32*)(gp), (las_u32*)(lp), 16, 0, 0)

__device__ __forceinline__ unsigned short f2bf(float f) {
  union { float f; unsigned u; } c; c.f = f;
  unsigned r = c.u + 0x7fffu + ((c.u >> 16) & 1u);   // RNE
  return (unsigned short)(r >> 16);
}
// pack two fp32 -> two bf16 (round-half-up): 2 adds + 1 v_perm
__device__ __forceinline__ unsigned packbf2(float a, float b) {
  unsigned ua = __float_as_uint(a) + 0x8000u;
  unsigned ub = __float_as_uint(b) + 0x8000u;
  return __builtin_amdgcn_perm(ub, ua, 0x07060302);  // [ub.hi16 | ua.hi16]
}

// ---------------- workspace layout (bytes) ----------------------------------
// control block (memset to 0 each call): 0..8192
static const size_t OFF_PCNT  = 0;        // 28*8 ints (pair counts, spread x8)
static const size_t OFF_PCUR  = 896;      // 28 ints (scatter cursors)
static const size_t OFF_ZPART = 1024;     // 64 floats
static const size_t OFF_PPART = 1280;     // 64*8 floats -> 3328
static const size_t OFF_ECNT  = 3328;     // 8 ints (per-expert counts, f_i)
static const size_t OFF_SBINF = 3360;     // 96 u32: ea|eb<<8|rows<<16
static const size_t OFF_SBBAS = 3744;     // 96 u32: token base of s-block
static const size_t OFF_BLKT  = 4128;     // 1 int
static const size_t OFF_PBASE = 4160;     // 28 ints (pair token base)
// data
static const size_t OFF_REXP  = 8192;     // 8192 u32
static const size_t OFF_RWTS  = 40960;    // 8192 float2 -> 106496
static const size_t OFF_IDS   = 106496;   // 8192 int    -> 139264
static const size_t OFF_WTS   = 139264;   // 8192 float2 -> 204800
static const size_t OFF_W2T   = 1048576;  // 8*1024*2048 bf16 (32MB)
static const size_t OFF_MT    = OFF_W2T + 33554432;   // 8*1024*1024 bf16 (16MB)
// XB (16MB) ALIASES W2T (dead after gemm_mt; convert_x runs after gemm_mt).
static const size_t OFF_XB    = OFF_W2T;
// total: 51,380,224 bytes (unchanged vs prior rounds)

// ---------------- 1. router (fp32 logits) + pair counting -------------------
__global__ __launch_bounds__(256)
void router_kernel(const float* __restrict__ x, const float* __restrict__ wrt,
                   unsigned* __restrict__ rexp, float2* __restrict__ rwts,
                   float* __restrict__ zpart, float* __restrict__ ppart,
                   int* __restrict__ pcnt) {
  int w = threadIdx.x >> 6, ln = threadIdx.x & 63;
  int t = blockIdx.x * 4 + w;
  const float* xr = x + (size_t)t * DD;
  float acc[8] = {0.f, 0.f, 0.f, 0.f, 0.f, 0.f, 0.f, 0.f};
  for (int i = 0; i < 16; ++i) {
    int d = ln + (i << 6);
    float xv = xr[d];
    float4 r0 = *(const float4*)(wrt + (size_t)d * 8);
    float4 r1 = *(const float4*)(wrt + (size_t)d * 8 + 4);
    acc[0] += xv * r0.x;  acc[1] += xv * r0.y;
    acc[2] += xv * r0.z;  acc[3] += xv * r0.w;
    acc[4] += xv * r1.x;  acc[5] += xv * r1.y;
    acc[6] += xv * r1.z;  acc[7] += xv * r1.w;
  }
#pragma unroll
  for (int e = 0; e < 8; ++e) {
#pragma unroll
    for (int off = 32; off > 0; off >>= 1) acc[e] += __shfl_xor(acc[e], off, 64);
  }
  if (ln == 0) {
    float m = acc[0];
#pragma unroll
    for (int e = 1; e < 8; ++e) m = fmaxf(m, acc[e]);
    float p[8], s = 0.f;
#pragma unroll
    for (int e = 0; e < 8; ++e) { p[e] = expf(acc[e] - m); s += p[e]; }
    float z = m + logf(s);
    // top-2, ties -> lowest index (matches lax.top_k)
    int e1 = 0; float v1 = acc[0];
#pragma unroll
    for (int e = 1; e < 8; ++e) if (acc[e] > v1) { v1 = acc[e]; e1 = e; }
    int e2 = (e1 == 0) ? 1 : 0; float v2 = acc[e2];
#pragma unroll
    for (int e = 0; e < 8; ++e) if (e != e1 && acc[e] > v2) { v2 = acc[e]; e2 = e; }
    float p1 = p[e1], p2 = p[e2];
    float inv = 1.f / (p1 + p2);
    rexp[t] = (unsigned)e1 | ((unsigned)e2 << 8);
    rwts[t] = make_float2(p1 * inv, p2 * inv);
    int sh = blockIdx.x & 63;   // contention-spread partials
    unsafeAtomicAdd(&zpart[sh], z * z);
    float sinv = 1.f / s;
#pragma unroll
    for (int e = 0; e < 8; ++e) unsafeAtomicAdd(&ppart[sh * 8 + e], p[e] * sinv);
    // pair count (spread x8 to cut contention)
    int ea = (e1 < e2) ? e1 : e2, eb = (e1 < e2) ? e2 : e1;
    atomicAdd(&pcnt[PIDX(ea, eb) * 8 + (blockIdx.x & 7)], 1);
  }
}

// ---------------- 2a. prefix: pair bases + s-block tables -------------------
__global__ void prefix_kernel(const int* __restrict__ pcnt, int* __restrict__ pbase,
                              unsigned* __restrict__ sbinf, unsigned* __restrict__ sbbas,
                              int* __restrict__ blkt) {
  if (threadIdx.x != 0) return;
  int tb = 0, bb = 0, p = 0;
  for (int ea = 0; ea < 7; ++ea) {
    for (int eb = ea + 1; eb < 8; ++eb) {
      int c = 0;
#pragma unroll
      for (int g = 0; g < 8; ++g) c += pcnt[p * 8 + g];
      pbase[p] = tb;
      int nb = (c + 127) >> 7;
      for (int k = 0; k < nb; ++k) {
        int rows = c - k * 128; if (rows > 128) rows = 128;
        sbinf[bb + k] = (unsigned)ea | ((unsigned)eb << 8) | ((unsigned)rows << 16);
        sbbas[bb + k] = (unsigned)(tb + k * 128);
      }
      tb += c; bb += nb; ++p;
    }
  }
  *blkt = bb;
}

// ---------------- 2b. scatter tokens into pair lists ------------------------
__global__ __launch_bounds__(256)
void scatter_kernel(const unsigned* __restrict__ rexp, const float2* __restrict__ rwts,
                    const int* __restrict__ pbase, int* __restrict__ pcur,
                    int* __restrict__ ecnt, int* __restrict__ ids,
                    float2* __restrict__ wts) {
  __shared__ int lcnt[8];
  if (threadIdx.x < 8) lcnt[threadIdx.x] = 0;
  __syncthreads();
  int t = blockIdx.x * 256 + threadIdx.x;
  unsigned re = rexp[t];
  float2 w = rwts[t];
  int e1 = (int)(re & 0xffu), e2 = (int)((re >> 8) & 0xffu);
  atomicAdd(&lcnt[e1], 1);
  atomicAdd(&lcnt[e2], 1);
  int ea, eb; float wa, wb;
  if (e1 < e2) { ea = e1; eb = e2; wa = w.x; wb = w.y; }
  else         { ea = e2; eb = e1; wa = w.y; wb = w.x; }
  int pid = PIDX(ea, eb);
  int slot = atomicAdd(&pcur[pid], 1);
  int idx = pbase[pid] + slot;
  ids[idx] = t;
  wts[idx] = make_float2(wa, wb);
  __syncthreads();
  if (threadIdx.x < 8) atomicAdd(&ecnt[threadIdx.x], lcnt[threadIdx.x]);
}

// ---------------- 3. W2 (fp32 [e*FF+f][j]) -> W2T (bf16 [e][j][f]) ----------
__global__ __launch_bounds__(256)
void transpose_w2_kernel(const float* __restrict__ w2, ushort_t* __restrict__ W2T) {
  __shared__ ushort_t tile[64 * 72];    // row stride 72 u16 (144B, 16B-aligned)
  int e = blockIdx.z, f0 = blockIdx.x * 64, j0 = blockIdx.y * 64;
  int tid = (int)threadIdx.x;
  int r = tid >> 2, c0 = (tid & 3) * 16;
  const float* src = w2 + ((size_t)(e * FF + f0 + r)) * DD + j0 + c0;
  float4 v0 = *(const float4*)(src);
  float4 v1 = *(const float4*)(src + 4);
  float4 v2 = *(const float4*)(src + 8);
  float4 v3 = *(const float4*)(src + 12);
  uint4 pa = make_uint4(packbf2(v0.x, v0.y), packbf2(v0.z, v0.w),
                        packbf2(v1.x, v1.y), packbf2(v1.z, v1.w));
  uint4 pb = make_uint4(packbf2(v2.x, v2.y), packbf2(v2.z, v2.w),
                        packbf2(v3.x, v3.y), packbf2(v3.z, v3.w));
  *(uint4*)&tile[r * 72 + c0]     = pa;
  *(uint4*)&tile[r * 72 + c0 + 8] = pb;
  __syncthreads();
  int j = tid >> 2, g0 = (tid & 3) * 16;
  ushort_t o[16];
#pragma unroll
  for (int i = 0; i < 16; ++i) o[i] = tile[(g0 + i) * 72 + j];
  ushort_t* dst = W2T + ((size_t)(e * DD + j0 + j)) * FF + f0 + g0;
  *(uint4*)(dst)     = *(uint4*)&o[0];
  *(uint4*)(dst + 8) = *(uint4*)&o[8];
}

// ---------------- 3b. x (fp32) -> XB (bf16), layout-preserving --------------
__global__ __launch_bounds__(256)
void convert_x_kernel(const float* __restrict__ x, ushort_t* __restrict__ XB) {
  size_t i = ((size_t)blockIdx.x * 256 + threadIdx.x) * 8;   // 8 floats/thread
  float4 f0 = *(const float4*)(x + i);
  float4 f1 = *(const float4*)(x + i + 4);
  uint4 pk = make_uint4(packbf2(f0.x, f0.y), packbf2(f0.z, f0.w),
                        packbf2(f1.x, f1.y), packbf2(f1.z, f1.w));
  *(uint4*)(XB + i) = pk;
}

// ---------------- 4. MT_e[m=j][n=i] = sum_f W2T[j][f] * W1[i][f] ------------
// grid (NE, DD/BM, DD/BN): blockIdx.x = e -> XCD affinity (W2T_e panel).
// Double-buffered: A via global_load_lds (prefetch t+2), B via f32-reg
// prefetch + pack/ds_write between barriers. Static LDS = 65536 B.
__global__ __launch_bounds__(256)
void gemm_mt_kernel(const ushort_t* __restrict__ W2T, const float* __restrict__ w1,
                    ushort_t* __restrict__ MT) {
  int e  = blockIdx.x;
  int m0 = blockIdx.y * BM;   // m = output dim j (W2 col)
  int n0 = blockIdx.z * BN;   // n = input dim i (W1 row)
  __shared__ alignas(16) ushort_t As[2][BM * BK];
  __shared__ alignas(16) ushort_t Bs[2][BN * BK];
  const ushort_t* Abase = W2T + (size_t)e * DD * FF;
  int tid = (int)threadIdx.x;
  int w = tid >> 6, ln = tid & 63;
  int wr = w >> 1, wc = w & 1;
  int mrow = ln & 15, kq = ln >> 4;
  const ushort_t* agp[4];
#pragma unroll
  for (int it = 0; it < 4; ++it) {
    int r  = w * 32 + it * 8 + (ln >> 3);
    int cs = (ln & 7) ^ (r & 7);
    agp[it] = Abase + (size_t)(m0 + r) * FF + cs * 8;
  }
  const float* bgp[4];
  int brq[4];
#pragma unroll
  for (int it = 0; it < 4; ++it) {
    int r = it * 32 + (tid >> 3), q = tid & 7;
    bgp[it] = w1 + (size_t)(n0 + r) * W1ROW + e * FF + q * 8;
    brq[it] = r * BK + ((q ^ (r & 7)) << 3);
  }
  float4 rb0[4], rb1[4];

#define MT_ISSUE_A(t, b)                                              \
  {  _Pragma("unroll")                                                \
     for (int it = 0; it < 4; ++it)                                   \
       GLOAD16(agp[it] + (t) * BK, &As[b][(w * 32 + it * 8) * BK]); }
#define MT_LOAD_B(t)                                                  \
  {  _Pragma("unroll")                                                \
     for (int it = 0; it < 4; ++it) {                                 \
       rb0[it] = *(const float4*)(bgp[it] + (t) * BK);                \
       rb1[it] = *(const float4*)(bgp[it] + (t) * BK + 4); } }
#define MT_PACK_B(b)                                                  \
  {  _Pragma("unroll")                                                \
     for (int it = 0; it < 4; ++it) {                                 \
       uint4 pk = make_uint4(packbf2(rb0[it].x, rb0[it].y),           \
                             packbf2(rb0[it].z, rb0[it].w),           \
                             packbf2(rb1[it].x, rb1[it].y),           \
                             packbf2(rb1[it].z, rb1[it].w));          \
       *(uint4*)&Bs[b][brq[it]] = pk; } }

  MT_ISSUE_A(0, 0);
  MT_LOAD_B(0);
  __syncthreads();
  MT_PACK_B(0);
  MT_ISSUE_A(1, 1);
  MT_LOAD_B(1);
  __syncthreads();

  floatx4 acc[4][4] = {};
  const int NT = FF / BK;          // 32
  for (int t = 0; t < NT; ++t) {
    int b = t & 1;
#pragma unroll
    for (int s = 0; s < 2; ++s) {
      short8 fa[4], fb[4];
#pragma unroll
      for (int i = 0; i < 4; ++i) {
        int r = wr * 64 + i * 16 + mrow;
        fa[i] = *(const short8*)&As[b][r * BK + ((((s << 2) | kq) ^ (r & 7)) << 3)];
      }
#pragma unroll
      for (int j = 0; j < 4; ++j) {
        int r = wc * 64 + j * 16 + mrow;
        fb[j] = *(const short8*)&Bs[b][r * BK + ((((s << 2) | kq) ^ (r & 7)) << 3)];
      }
#pragma unroll
      for (int i = 0; i < 4; ++i)
#pragma unroll
        for (int j = 0; j < 4; ++j)
          acc[i][j] = __builtin_amdgcn_mfma_f32_16x16x32_bf16(fa[i], fb[j], acc[i][j], 0, 0, 0);
    }
    if (t + 1 < NT) {
      __syncthreads();
      MT_PACK_B(b ^ 1);
      __syncthreads();
      if (t + 2 < NT) {
        MT_ISSUE_A(t + 2, b);
        MT_LOAD_B(t + 2);
      }
    }
  }
  ushort_t* outp = MT + (size_t)e * DD * DD;
#pragma unroll
  for (int i = 0; i < 4; ++i) {
#pragma unroll
    for (int j = 0; j < 4; ++j) {
#pragma unroll
      for (int rr = 0; rr < 4; ++rr) {
        int m = m0 + wr * 64 + i * 16 + kq * 4 + rr;
        int n = n0 + wc * 64 + j * 16 + mrow;
        outp[(size_t)m * DD + n] = f2bf(acc[i][j][rr]);
      }
    }
  }
#undef MT_ISSUE_A
#undef MT_LOAD_B
#undef MT_PACK_B
}

// ---------------- 5. pair GEMM: out[tok] = wa*(x@M_ea) + wb*(x@M_eb) --------
// grid (SBMAX=96, 8): s-block from chunked swizzle (XCD c gets contiguous
// s-range -> XB rows fetched ~once per XCD, few experts' MT panels).
// 32 K-steps: 16 over M_ea (accA), 16 over M_eb (accB). Plain stores, no
// atomics. Static LDS = 65536 B.
__global__ __launch_bounds__(256)
void gemm_pair_kernel(const ushort_t* __restrict__ XB, const ushort_t* __restrict__ MT,
                      const unsigned* __restrict__ sbinf, const unsigned* __restrict__ sbbas,
                      const int* __restrict__ blkt, const int* __restrict__ ids,
                      const float2* __restrict__ wts, float* __restrict__ outp) {
  int lin = blockIdx.x;
  int sb = (lin & 7) * (SBMAX / 8) + (lin >> 3);   // chunked XCD swizzle
  if (sb >= *blkt) return;
  unsigned info = sbinf[sb];
  int tokoff = (int)sbbas[sb];
  int ea = (int)(info & 0xffu), eb = (int)((info >> 8) & 0xffu);
  int rows = (int)((info >> 16) & 0xffu);
  int n0 = blockIdx.y * BN;
  __shared__ alignas(16) ushort_t As[2][BM * BK];
  __shared__ alignas(16) ushort_t Bs[2][BN * BK];
  int tid = (int)threadIdx.x;
  const int* idsE = ids + tokoff;
  const float2* wtsE = wts + tokoff;
  const ushort_t* Ba = MT + (size_t)ea * DD * DD;
  const ushort_t* Bb = MT + (size_t)eb * DD * DD;
  int w = tid >> 6, ln = tid & 63;
  int wr = w >> 1, wc = w & 1;
  int mrow = ln & 15, kq = ln >> 4;
  // per-lane A (gathered token rows) / B (MT row offsets), source-swizzled
  const ushort_t* agp[4];
  int bofs[4];
#pragma unroll
  for (int it = 0; it < 4; ++it) {
    int r  = w * 32 + it * 8 + (ln >> 3);
    int cs = (ln & 7) ^ (r & 7);
    int tok = (r < rows) ? idsE[r] : idsE[0];   // broadcast load (8 lanes/r)
    agp[it] = XB + (size_t)tok * DD + cs * 8;
    bofs[it] = (n0 + r) * DD + cs * 8;
  }

#define P_ISSUE(t, b)                                                      \
  {  _Pragma("unroll")                                                     \
     for (int it = 0; it < 4; ++it)                                        \
       GLOAD16(agp[it] + ((t) & 15) * BK, &As[b][(w * 32 + it * 8) * BK]); \
     const ushort_t* Bx = ((t) < 16) ? Ba : Bb;                            \
     _Pragma("unroll")                                                     \
     for (int it = 0; it < 4; ++it)                                        \
       GLOAD16(Bx + bofs[it] + ((t) & 15) * BK, &Bs[b][(w * 32 + it * 8) * BK]); }

  P_ISSUE(0, 0);
  __syncthreads();
  P_ISSUE(1, 1);

  floatx4 accA[4][4] = {};
  floatx4 accB[4][4] = {};
  const int NT = 32;
  for (int t = 0; t < NT; ++t) {
    int b = t & 1;
#pragma unroll
    for (int s = 0; s < 2; ++s) {
      short8 fa[4], fb[4];
#pragma unroll
      for (int i = 0; i < 4; ++i) {
        int r = wr * 64 + i * 16 + mrow;
        fa[i] = *(const short8*)&As[b][r * BK + ((((s << 2) | kq) ^ (r & 7)) << 3)];
      }
#pragma unroll
      for (int j = 0; j < 4; ++j) {
        int r = wc * 64 + j * 16 + mrow;
        fb[j] = *(const short8*)&Bs[b][r * BK + ((((s << 2) | kq) ^ (r & 7)) << 3)];
      }
      if (t < 16) {
#pragma unroll
        for (int i = 0; i < 4; ++i)
#pragma unroll
          for (int j = 0; j < 4; ++j)
            accA[i][j] = __builtin_amdgcn_mfma_f32_16x16x32_bf16(fa[i], fb[j], accA[i][j], 0, 0, 0);
      } else {
#pragma unroll
        for (int i = 0; i < 4; ++i)
#pragma unroll
          for (int j = 0; j < 4; ++j)
            accB[i][j] = __builtin_amdgcn_mfma_f32_16x16x32_bf16(fa[i], fb[j], accB[i][j], 0, 0, 0);
      }
    }
    if (t + 1 < NT) {
      __syncthreads();                       // drains t+1 loads (flew during t)
      if (t + 2 < NT) P_ISSUE(t + 2, b);     // into freed buf
    }
  }
  // epilogue: PLAIN stores, each out element written exactly once
#pragma unroll
  for (int i = 0; i < 4; ++i) {
#pragma unroll
    for (int rr = 0; rr < 4; ++rr) {
      int mloc = wr * 64 + i * 16 + kq * 4 + rr;
      if (mloc < rows) {
        int    tok = idsE[mloc];
        float2 wv  = wtsE[mloc];
        float* orow = outp + (size_t)tok * DD;
#pragma unroll
        for (int j = 0; j < 4; ++j) {
          int ncol = n0 + wc * 64 + j * 16 + mrow;
          orow[ncol] = wv.x * accA[i][j][rr] + wv.y * accB[i][j][rr];
        }
      }
    }
  }
#undef P_ISSUE
}

// ---------------- 6. losses + f_i (wave-parallel) ---------------------------
__global__ void losses_kernel(const float* __restrict__ zpart, const float* __restrict__ ppart,
                              const int* __restrict__ ecnt, float* __restrict__ outaux) {
  int ln = threadIdx.x & 63;          // one wave
  float z = zpart[ln];
  float p8[8];
#pragma unroll
  for (int e = 0; e < 8; ++e) p8[e] = ppart[ln * 8 + e];
#pragma unroll
  for (int off = 32; off > 0; off >>= 1) {
    z += __shfl_xor(z, off, 64);
#pragma unroll
    for (int e = 0; e < 8; ++e) p8[e] += __shfl_xor(p8[e], off, 64);
  }
  if (ln == 0) {
    float lb = 0.f;
#pragma unroll
    for (int e = 0; e < 8; ++e) {
      float fi = (float)ecnt[e] / (float)(T_TOK * 2);
      lb += fi * (p8[e] / (float)T_TOK);
      outaux[2 + e] = fi;
    }
    outaux[0] = z / (float)T_TOK;
    outaux[1] = lb * (float)NE;
  }
}

// ---------------- launch -----------------------------------------------------
extern "C" void kernel_launch(void* const* d_in, const int* in_sizes, int n_in,
                              void* d_out, int out_size, void* d_ws, size_t ws_size,
                              hipStream_t stream) {
  const float* x   = (const float*)d_in[0];   // [8192,1024] fp32
  const float* wrt = (const float*)d_in[1];   // [1024,8]    fp32
  const float* w1  = (const float*)d_in[2];   // [1024,16384] fp32
  const float* w2  = (const float*)d_in[3];   // [16384,1024] fp32
  float* out = (float*)d_out;                 // 8192*1024 + 1 + 1 + 8 fp32

  char* ws = (char*)d_ws;
  int*      pcnt  = (int*)     (ws + OFF_PCNT);
  int*      pcur  = (int*)     (ws + OFF_PCUR);
  float*    zpart = (float*)   (ws + OFF_ZPART);
  float*    ppart = (float*)   (ws + OFF_PPART);
  int*      ecnt  = (int*)     (ws + OFF_ECNT);
  unsigned* sbinf = (unsigned*)(ws + OFF_SBINF);
  unsigned* sbbas = (unsigned*)(ws + OFF_SBBAS);
  int*      blkt  = (int*)     (ws + OFF_BLKT);
  int*      pbase = (int*)     (ws + OFF_PBASE);
  unsigned* rexp  = (unsigned*)(ws + OFF_REXP);
  float2*   rwts  = (float2*)  (ws + OFF_RWTS);
  int*      ids   = (int*)     (ws + OFF_IDS);
  float2*   wtsf  = (float2*)  (ws + OFF_WTS);
  ushort_t* W2T   = (ushort_t*)(ws + OFF_W2T);
  ushort_t* MT    = (ushort_t*)(ws + OFF_MT);
  ushort_t* XB    = (ushort_t*)(ws + OFF_XB);  // aliases W2T

  hipMemsetAsync(d_ws, 0, 8192, stream);       // control block only (no out memset)
  router_kernel<<<T_TOK / 4, 256, 0, stream>>>(x, wrt, rexp, rwts, zpart, ppart, pcnt);
  prefix_kernel<<<1, 64, 0, stream>>>(pcnt, pbase, sbinf, sbbas, blkt);
  scatter_kernel<<<T_TOK / 256, 256, 0, stream>>>(rexp, rwts, pbase, pcur, ecnt, ids, wtsf);
  transpose_w2_kernel<<<dim3(FF / 64, DD / 64, NE), 256, 0, stream>>>(w2, W2T);
  gemm_mt_kernel<<<dim3(NE, DD / BM, DD / BN), 256, 0, stream>>>(W2T, w1, MT);
  convert_x_kernel<<<(T_TOK * DD) / (8 * 256), 256, 0, stream>>>(x, XB);  // after gemm_mt
  gemm_pair_kernel<<<dim3(SBMAX, DD / BN), 256, 0, stream>>>(XB, MT, sbinf, sbbas, blkt, ids, wtsf, out);
  losses_kernel<<<1, 64, 0, stream>>>(zpart, ppart, ecnt, out + (size_t)T_TOK * DD);
}

// Round 5
// 442.862 us; speedup vs baseline: 1.0384x; 1.0384x over previous
//
#include <hip/hip_runtime.h>
#include <hip/hip_bf16.h>
#include <stdint.h>
#include <stddef.h>

// ---------------------------------------------------------------------------
// MoE MLP. MT_e = (W1_e @ W2_e)^T precomputed; out[t] = wa*(x@M_ea)+wb*(x@M_eb)
// by unordered expert pair (28 pairs), plain stores (each out elem once).
// R5: BARRIER-FREE INNER LOOP in both GEMMs.
//   Evidence R0-R4: token GEMM pinned at 115-138us across 4 structures, all
//   pipes <15% busy -> per-K-step barrier convoy (every __syncthreads drains
//   vmcnt(0), stages serialize). Fix:
//   - A-fragments loaded DIRECT from global (lane l: row(l&15), 16B at
//     k=(l>>4)*8) — no A LDS at all.
//   - B: one 32KB panel [128n][128k] per phase (XOR-swizzled, 0-conflict),
//     then 4 K-steps with ZERO barriers (2 A-gathers + 8 ds_read + 16 MFMA
//     per wave-step). 2 barriers/phase total.
//   - 32KB LDS + __launch_bounds__(256,3) -> 3 blocks/CU for cross-block
//     stage/compute overlap (R1's 4-block > R3's 2-block was the only lever
//     that ever moved the number).
//   - accA/accB fused via wa/wb ratio rescale between expert passes.
//   - prefix_kernel parallelized (was 1-thread serial global chain).
// ---------------------------------------------------------------------------

typedef unsigned short ushort_t;                                   // bf16 bits
typedef __attribute__((ext_vector_type(8))) short short8;          // MFMA A/B frag
typedef __attribute__((ext_vector_type(4))) float floatx4;         // MFMA C/D frag

#define T_TOK 8192
#define NE    8
#define DD    1024
#define FF    2048
#define W1ROW (NE * FF)     // 16384
#define NPAIR 28
#define SBMAX 96            // >= 28 + 8192/128 = 92, multiple of 8

#define BM 128
#define BN 128

// pair id for ea<eb: compact 0..27
#define PIDX(ea, eb) ((ea) * (15 - (ea)) / 2 + (eb) - (ea) - 1)

typedef const __attribute__((address_space(1))) unsigned int gas_u32;
typedef __attribute__((address_space(3)))       unsigned int las_u32;
// async global->LDS, 16B/lane, LDS dest = wave-uniform base + lane*16
#define GLOAD16(gp, lp) \
  __builtin_amdgcn_global_load_lds((gas_u32*)(gp), (las_u32*)(lp), 16, 0, 0)

__device__ __forceinline__ unsigned short f2bf(float f) {
  union { float f; unsigned u; } c; c.f = f;
  unsigned r = c.u + 0x7fffu + ((c.u >> 16) & 1u);   // RNE
  return (unsigned short)(r >> 16);
}
// pack two fp32 -> two bf16 (round-half-up): 2 adds + 1 v_perm
__device__ __forceinline__ unsigned packbf2(float a, float b) {
  unsigned ua = __float_as_uint(a) + 0x8000u;
  unsigned ub = __float_as_uint(b) + 0x8000u;
  return __builtin_amdgcn_perm(ub, ua, 0x07060302);  // [ub.hi16 | ua.hi16]
}

#define MFMA16(a, b, c) __builtin_amdgcn_mfma_f32_16x16x32_bf16((a), (b), (c), 0, 0, 0)

// ---------------- workspace layout (bytes) ----------------------------------
static const size_t OFF_PCNT  = 0;        // 28*8 ints
static const size_t OFF_PCUR  = 896;      // 28 ints
static const size_t OFF_ZPART = 1024;     // 64 floats
static const size_t OFF_PPART = 1280;     // 64*8 floats -> 3328
static const size_t OFF_ECNT  = 3328;     // 8 ints
static const size_t OFF_SBINF = 3360;     // 96 u32
static const size_t OFF_SBBAS = 3744;     // 96 u32
static const size_t OFF_BLKT  = 4128;     // 1 int
static const size_t OFF_PBASE = 4160;     // 28 ints
static const size_t OFF_REXP  = 8192;     // 8192 u32
static const size_t OFF_RWTS  = 40960;    // 8192 float2 -> 106496
static const size_t OFF_IDS   = 106496;   // 8192 int    -> 139264
static const size_t OFF_WTS   = 139264;   // 8192 float2 -> 204800
static const size_t OFF_W2T   = 1048576;  // 8*1024*2048 bf16 (32MB)
static const size_t OFF_MT    = OFF_W2T + 33554432;   // 16MB
static const size_t OFF_XB    = OFF_W2T;  // aliases W2T (dead after gemm_mt)
// total 51,380,224 bytes (unchanged)

// ---------------- 1. router + pair counting ---------------------------------
__global__ __launch_bounds__(256)
void router_kernel(const float* __restrict__ x, const float* __restrict__ wrt,
                   unsigned* __restrict__ rexp, float2* __restrict__ rwts,
                   float* __restrict__ zpart, float* __restrict__ ppart,
                   int* __restrict__ pcnt) {
  int w = threadIdx.x >> 6, ln = threadIdx.x & 63;
  int t = blockIdx.x * 4 + w;
  const float* xr = x + (size_t)t * DD;
  float acc[8] = {0.f, 0.f, 0.f, 0.f, 0.f, 0.f, 0.f, 0.f};
  for (int i = 0; i < 16; ++i) {
    int d = ln + (i << 6);
    float xv = xr[d];
    float4 r0 = *(const float4*)(wrt + (size_t)d * 8);
    float4 r1 = *(const float4*)(wrt + (size_t)d * 8 + 4);
    acc[0] += xv * r0.x;  acc[1] += xv * r0.y;
    acc[2] += xv * r0.z;  acc[3] += xv * r0.w;
    acc[4] += xv * r1.x;  acc[5] += xv * r1.y;
    acc[6] += xv * r1.z;  acc[7] += xv * r1.w;
  }
#pragma unroll
  for (int e = 0; e < 8; ++e) {
#pragma unroll
    for (int off = 32; off > 0; off >>= 1) acc[e] += __shfl_xor(acc[e], off, 64);
  }
  if (ln == 0) {
    float m = acc[0];
#pragma unroll
    for (int e = 1; e < 8; ++e) m = fmaxf(m, acc[e]);
    float p[8], s = 0.f;
#pragma unroll
    for (int e = 0; e < 8; ++e) { p[e] = expf(acc[e] - m); s += p[e]; }
    float z = m + logf(s);
    int e1 = 0; float v1 = acc[0];
#pragma unroll
    for (int e = 1; e < 8; ++e) if (acc[e] > v1) { v1 = acc[e]; e1 = e; }
    int e2 = (e1 == 0) ? 1 : 0; float v2 = acc[e2];
#pragma unroll
    for (int e = 0; e < 8; ++e) if (e != e1 && acc[e] > v2) { v2 = acc[e]; e2 = e; }
    float p1 = p[e1], p2 = p[e2];
    float inv = 1.f / (p1 + p2);
    rexp[t] = (unsigned)e1 | ((unsigned)e2 << 8);
    rwts[t] = make_float2(p1 * inv, p2 * inv);
    int sh = blockIdx.x & 63;
    unsafeAtomicAdd(&zpart[sh], z * z);
    float sinv = 1.f / s;
#pragma unroll
    for (int e = 0; e < 8; ++e) unsafeAtomicAdd(&ppart[sh * 8 + e], p[e] * sinv);
    int ea = (e1 < e2) ? e1 : e2, eb = (e1 < e2) ? e2 : e1;
    atomicAdd(&pcnt[PIDX(ea, eb) * 8 + (blockIdx.x & 7)], 1);
  }
}

// ---------------- 2a. prefix: pair bases + s-block tables (parallel) --------
__global__ void prefix_kernel(const int* __restrict__ pcnt, int* __restrict__ pbase,
                              unsigned* __restrict__ sbinf, unsigned* __restrict__ sbbas,
                              int* __restrict__ blkt) {
  __shared__ int c[NPAIR], tb_[NPAIR], cb_[NPAIR];
  int tid = (int)threadIdx.x;
  if (tid < NPAIR) {
    int s = 0;
#pragma unroll
    for (int g = 0; g < 8; ++g) s += pcnt[tid * 8 + g];
    c[tid] = s;
  }
  __syncthreads();
  if (tid == 0) {
    int tb = 0, bb = 0;
    for (int p = 0; p < NPAIR; ++p) {
      tb_[p] = tb; cb_[p] = bb;
      tb += c[p]; bb += (c[p] + 127) >> 7;
    }
    *blkt = bb;
  }
  __syncthreads();
  if (tid < NPAIR) {
    // decode pair id -> (ea, eb)
    int p = tid, ea = 0, span = 7;
    while (p >= span) { p -= span; ++ea; --span; }
    int eb = ea + 1 + p;
    int cc = c[tid], base = tb_[tid], b0 = cb_[tid];
    pbase[tid] = base;
    int nb = (cc + 127) >> 7;
    for (int k = 0; k < nb; ++k) {
      int rows = cc - k * 128; if (rows > 128) rows = 128;
      sbinf[b0 + k] = (unsigned)ea | ((unsigned)eb << 8) | ((unsigned)rows << 16);
      sbbas[b0 + k] = (unsigned)(base + k * 128);
    }
  }
}

// ---------------- 2b. scatter tokens into pair lists ------------------------
__global__ __launch_bounds__(256)
void scatter_kernel(const unsigned* __restrict__ rexp, const float2* __restrict__ rwts,
                    const int* __restrict__ pbase, int* __restrict__ pcur,
                    int* __restrict__ ecnt, int* __restrict__ ids,
                    float2* __restrict__ wts) {
  __shared__ int lcnt[8];
  if (threadIdx.x < 8) lcnt[threadIdx.x] = 0;
  __syncthreads();
  int t = blockIdx.x * 256 + threadIdx.x;
  unsigned re = rexp[t];
  float2 w = rwts[t];
  int e1 = (int)(re & 0xffu), e2 = (int)((re >> 8) & 0xffu);
  atomicAdd(&lcnt[e1], 1);
  atomicAdd(&lcnt[e2], 1);
  int ea, eb; float wa, wb;
  if (e1 < e2) { ea = e1; eb = e2; wa = w.x; wb = w.y; }
  else         { ea = e2; eb = e1; wa = w.y; wb = w.x; }
  int pid = PIDX(ea, eb);
  int slot = atomicAdd(&pcur[pid], 1);
  int idx = pbase[pid] + slot;
  ids[idx] = t;
  wts[idx] = make_float2(wa, wb);
  __syncthreads();
  if (threadIdx.x < 8) atomicAdd(&ecnt[threadIdx.x], lcnt[threadIdx.x]);
}

// ---------------- 3. W2 (fp32 [e*FF+f][j]) -> W2T (bf16 [e][j][f]) ----------
__global__ __launch_bounds__(256)
void transpose_w2_kernel(const float* __restrict__ w2, ushort_t* __restrict__ W2T) {
  __shared__ ushort_t tile[64 * 72];
  int e = blockIdx.z, f0 = blockIdx.x * 64, j0 = blockIdx.y * 64;
  int tid = (int)threadIdx.x;
  int r = tid >> 2, c0 = (tid & 3) * 16;
  const float* src = w2 + ((size_t)(e * FF + f0 + r)) * DD + j0 + c0;
  float4 v0 = *(const float4*)(src);
  float4 v1 = *(const float4*)(src + 4);
  float4 v2 = *(const float4*)(src + 8);
  float4 v3 = *(const float4*)(src + 12);
  uint4 pa = make_uint4(packbf2(v0.x, v0.y), packbf2(v0.z, v0.w),
                        packbf2(v1.x, v1.y), packbf2(v1.z, v1.w));
  uint4 pb = make_uint4(packbf2(v2.x, v2.y), packbf2(v2.z, v2.w),
                        packbf2(v3.x, v3.y), packbf2(v3.z, v3.w));
  *(uint4*)&tile[r * 72 + c0]     = pa;
  *(uint4*)&tile[r * 72 + c0 + 8] = pb;
  __syncthreads();
  int j = tid >> 2, g0 = (tid & 3) * 16;
  ushort_t o[16];
#pragma unroll
  for (int i = 0; i < 16; ++i) o[i] = tile[(g0 + i) * 72 + j];
  ushort_t* dst = W2T + ((size_t)(e * DD + j0 + j)) * FF + f0 + g0;
  *(uint4*)(dst)     = *(uint4*)&o[0];
  *(uint4*)(dst + 8) = *(uint4*)&o[8];
}

// ---------------- 3b. x (fp32) -> XB (bf16) ---------------------------------
__global__ __launch_bounds__(256)
void convert_x_kernel(const float* __restrict__ x, ushort_t* __restrict__ XB) {
  size_t i = ((size_t)blockIdx.x * 256 + threadIdx.x) * 8;
  float4 f0 = *(const float4*)(x + i);
  float4 f1 = *(const float4*)(x + i + 4);
  uint4 pk = make_uint4(packbf2(f0.x, f0.y), packbf2(f0.z, f0.w),
                        packbf2(f1.x, f1.y), packbf2(f1.z, f1.w));
  *(uint4*)(XB + i) = pk;
}

// ---------------- 4. MT_e[m=j][n=i] = sum_f W2T[j][f] * W1[i][f] ------------
// A = W2T rows, DIRECT per-fragment global gathers (no LDS). B = w1 fp32,
// reg-pack staged into one 32KB swizzled panel per 128-f phase; inner 4
// K-steps barrier-free. 2 barriers/phase, 16 phases.
__global__ __launch_bounds__(256, 3)
void gemm_mt_kernel(const ushort_t* __restrict__ W2T, const float* __restrict__ w1,
                    ushort_t* __restrict__ MT) {
  int e  = blockIdx.x;
  int m0 = blockIdx.y * BM;
  int n0 = blockIdx.z * BN;
  __shared__ alignas(16) ushort_t Bs[128 * 128];   // 32 KB
  int tid = (int)threadIdx.x;
  int w = tid >> 6, ln = tid & 63;
  int mrow = ln & 15, kq = ln >> 4;
  const ushort_t* Abase = W2T + (size_t)e * DD * FF;
  // A per-lane fragment bases (i = 0,1): row m0 + w*32 + i*16 + mrow
  const ushort_t* aP[2];
#pragma unroll
  for (int i = 0; i < 2; ++i)
    aP[i] = Abase + (size_t)(m0 + w * 32 + i * 16 + mrow) * FF + kq * 8;
  // B stage slots: 8 per thread; slot -> (n, qs); source chunk q = invswz(qs)
  const float* bSrc[8];
  int bDst[8];
#pragma unroll
  for (int it = 0; it < 8; ++it) {
    int slot = it * 256 + tid;
    int n = slot >> 4, qs = slot & 15;
    int q = (qs & 8) | ((qs ^ n) & 7);
    bSrc[it] = w1 + (size_t)(n0 + n) * W1ROW + e * FF + q * 8;
    bDst[it] = slot * 8;            // (n*16+qs)*8 ushorts
  }
  floatx4 acc[2][8] = {};
  for (int p = 0; p < 16; ++p) {
    int kb = p * 128;
    // stage B panel: 2 groups of 4 slots (8 float4 in flight each)
#pragma unroll
    for (int g = 0; g < 2; ++g) {
      float4 r0[4], r1[4];
#pragma unroll
      for (int u = 0; u < 4; ++u) {
        const float* sp = bSrc[g * 4 + u] + kb;
        r0[u] = *(const float4*)(sp);
        r1[u] = *(const float4*)(sp + 4);
      }
#pragma unroll
      for (int u = 0; u < 4; ++u) {
        uint4 pk = make_uint4(packbf2(r0[u].x, r0[u].y), packbf2(r0[u].z, r0[u].w),
                              packbf2(r1[u].x, r1[u].y), packbf2(r1[u].z, r1[u].w));
        *(uint4*)&Bs[bDst[g * 4 + u]] = pk;
      }
    }
    __syncthreads();                 // panel ready
    // 4 barrier-free K-steps, A direct from global with 1-step lookahead
    short8 na = *(const short8*)(aP[0] + kb);
    short8 nb = *(const short8*)(aP[1] + kb);
#pragma unroll
    for (int t = 0; t < 4; ++t) {
      short8 fa0 = na, fa1 = nb;
      if (t < 3) {
        na = *(const short8*)(aP[0] + kb + (t + 1) * 32);
        nb = *(const short8*)(aP[1] + kb + (t + 1) * 32);
      }
      int c = 4 * t + kq;
#pragma unroll
      for (int j = 0; j < 8; ++j) {
        int n = j * 16 + mrow;
        int ch = (c & 8) | ((c ^ n) & 7);
        short8 fb = *(const short8*)&Bs[n * 128 + ch * 8];
        acc[0][j] = MFMA16(fa0, fb, acc[0][j]);
        acc[1][j] = MFMA16(fa1, fb, acc[1][j]);
      }
    }
    __syncthreads();                 // readers done before next overwrite
  }
  // epilogue: C/D layout col=lane&15, row=(lane>>4)*4+reg
  ushort_t* outp = MT + (size_t)e * DD * DD;
#pragma unroll
  for (int i = 0; i < 2; ++i) {
#pragma unroll
    for (int rr = 0; rr < 4; ++rr) {
      int m = m0 + w * 32 + i * 16 + kq * 4 + rr;
#pragma unroll
      for (int j = 0; j < 8; ++j) {
        int n = n0 + j * 16 + mrow;
        outp[(size_t)m * DD + n] = f2bf(acc[i][j][rr]);
      }
    }
  }
}

// ---------------- 5. pair GEMM: out[tok] = wa*(x@M_ea) + wb*(x@M_eb) --------
// A = gathered XB token rows, DIRECT per-fragment global gathers (no LDS).
// B = MT panel 32KB per 128-k phase via global_load_lds (source-swizzled,
// linear dest). Inner 4 K-steps barrier-free. 16 phases: p<8 expert ea,
// p>=8 expert eb; single accumulator with wa/wb ratio rescale at p==7.
__global__ __launch_bounds__(256, 3)
void gemm_pair_kernel(const ushort_t* __restrict__ XB, const ushort_t* __restrict__ MT,
                      const unsigned* __restrict__ sbinf, const unsigned* __restrict__ sbbas,
                      const int* __restrict__ blkt, const int* __restrict__ ids,
                      const float2* __restrict__ wts, float* __restrict__ outp) {
  int lin = blockIdx.x;
  int sb = (lin & 7) * (SBMAX / 8) + (lin >> 3);   // chunked XCD swizzle
  if (sb >= *blkt) return;
  unsigned info = sbinf[sb];
  int tokoff = (int)sbbas[sb];
  int ea = (int)(info & 0xffu), eb = (int)((info >> 8) & 0xffu);
  int rows = (int)((info >> 16) & 0x1ffu);
  int n0 = blockIdx.y * BN;
  __shared__ alignas(16) ushort_t Bs[128 * 128];   // 32 KB
  int tid = (int)threadIdx.x;
  int w = tid >> 6, ln = tid & 63;
  int mrow = ln & 15, kq = ln >> 4;
  const int* idsE = ids + tokoff;
  const float2* wtsE = wts + tokoff;
  const ushort_t* Ba = MT + (size_t)ea * DD * DD;
  const ushort_t* Bb = MT + (size_t)eb * DD * DD;
  // B stage slots (8 per thread): source-chunk swizzle, linear LDS dest
  int bOfs[8];
#pragma unroll
  for (int it = 0; it < 8; ++it) {
    int slot = it * 256 + tid;
    int n = slot >> 4, qs = slot & 15;
    int q = (qs & 8) | ((qs ^ n) & 7);
    bOfs[it] = (n0 + n) * DD + q * 8;
  }
  // A per-lane token-row fragment bases (i = 0,1)
  const ushort_t* aP[2];
#pragma unroll
  for (int i = 0; i < 2; ++i) {
    int r = w * 32 + i * 16 + mrow;
    int tok = (r < rows) ? idsE[r] : idsE[0];
    aP[i] = XB + (size_t)tok * DD + kq * 8;
  }
  floatx4 acc[2][8] = {};
  for (int p = 0; p < 16; ++p) {
    const ushort_t* Bx = (p < 8) ? Ba : Bb;
    int kb = (p & 7) * 128;
    // stage B panel (gload_lds: wave-uniform dest base + lane*16)
#pragma unroll
    for (int it = 0; it < 8; ++it)
      GLOAD16(Bx + bOfs[it] + kb, &Bs[(it * 256 + w * 64) * 8]);
    __syncthreads();                 // drain stage -> panel ready
    // 4 barrier-free K-steps
    short8 na = *(const short8*)(aP[0] + kb);
    short8 nb = *(const short8*)(aP[1] + kb);
#pragma unroll
    for (int t = 0; t < 4; ++t) {
      short8 fa0 = na, fa1 = nb;
      if (t < 3) {
        na = *(const short8*)(aP[0] + kb + (t + 1) * 32);
        nb = *(const short8*)(aP[1] + kb + (t + 1) * 32);
      }
      int c = 4 * t + kq;
#pragma unroll
      for (int j = 0; j < 8; ++j) {
        int n = j * 16 + mrow;
        int ch = (c & 8) | ((c ^ n) & 7);
        short8 fb = *(const short8*)&Bs[n * 128 + ch * 8];
        acc[0][j] = MFMA16(fa0, fb, acc[0][j]);
        acc[1][j] = MFMA16(fa1, fb, acc[1][j]);
      }
    }
    if (p == 7) {
      // switch expert: acc = (wa/wb)*Sa, then accumulate Sb; store does *wb.
#pragma unroll
      for (int i = 0; i < 2; ++i) {
#pragma unroll
        for (int rr = 0; rr < 4; ++rr) {
          int r2 = w * 32 + i * 16 + kq * 4 + rr;
          float2 wv = (r2 < rows) ? wtsE[r2] : make_float2(1.f, 1.f);
          float ratio = wv.x / wv.y;
#pragma unroll
          for (int j = 0; j < 8; ++j) acc[i][j][rr] *= ratio;
        }
      }
    }
    __syncthreads();                 // readers done before next overwrite
  }
  // epilogue: plain stores, each out element written exactly once
#pragma unroll
  for (int i = 0; i < 2; ++i) {
#pragma unroll
    for (int rr = 0; rr < 4; ++rr) {
      int r2 = w * 32 + i * 16 + kq * 4 + rr;
      if (r2 < rows) {
        int tok = idsE[r2];
        float wb_ = wtsE[r2].y;
        float* orow = outp + (size_t)tok * DD + n0;
#pragma unroll
        for (int j = 0; j < 8; ++j)
          orow[j * 16 + mrow] = wb_ * acc[i][j][rr];
      }
    }
  }
}

// ---------------- 6. losses + f_i (wave-parallel) ---------------------------
__global__ void losses_kernel(const float* __restrict__ zpart, const float* __restrict__ ppart,
                              const int* __restrict__ ecnt, float* __restrict__ outaux) {
  int ln = threadIdx.x & 63;
  float z = zpart[ln];
  float p8[8];
#pragma unroll
  for (int e = 0; e < 8; ++e) p8[e] = ppart[ln * 8 + e];
#pragma unroll
  for (int off = 32; off > 0; off >>= 1) {
    z += __shfl_xor(z, off, 64);
#pragma unroll
    for (int e = 0; e < 8; ++e) p8[e] += __shfl_xor(p8[e], off, 64);
  }
  if (ln == 0) {
    float lb = 0.f;
#pragma unroll
    for (int e = 0; e < 8; ++e) {
      float fi = (float)ecnt[e] / (float)(T_TOK * 2);
      lb += fi * (p8[e] / (float)T_TOK);
      outaux[2 + e] = fi;
    }
    outaux[0] = z / (float)T_TOK;
    outaux[1] = lb * (float)NE;
  }
}

// ---------------- launch -----------------------------------------------------
extern "C" void kernel_launch(void* const* d_in, const int* in_sizes, int n_in,
                              void* d_out, int out_size, void* d_ws, size_t ws_size,
                              hipStream_t stream) {
  const float* x   = (const float*)d_in[0];   // [8192,1024] fp32
  const float* wrt = (const float*)d_in[1];   // [1024,8]    fp32
  const float* w1  = (const float*)d_in[2];   // [1024,16384] fp32
  const float* w2  = (const float*)d_in[3];   // [16384,1024] fp32
  float* out = (float*)d_out;                 // 8192*1024 + 1 + 1 + 8 fp32

  char* ws = (char*)d_ws;
  int*      pcnt  = (int*)     (ws + OFF_PCNT);
  int*      pcur  = (int*)     (ws + OFF_PCUR);
  float*    zpart = (float*)   (ws + OFF_ZPART);
  float*    ppart = (float*)   (ws + OFF_PPART);
  int*      ecnt  = (int*)     (ws + OFF_ECNT);
  unsigned* sbinf = (unsigned*)(ws + OFF_SBINF);
  unsigned* sbbas = (unsigned*)(ws + OFF_SBBAS);
  int*      blkt  = (int*)     (ws + OFF_BLKT);
  int*      pbase = (int*)     (ws + OFF_PBASE);
  unsigned* rexp  = (unsigned*)(ws + OFF_REXP);
  float2*   rwts  = (float2*)  (ws + OFF_RWTS);
  int*      ids   = (int*)     (ws + OFF_IDS);
  float2*   wtsf  = (float2*)  (ws + OFF_WTS);
  ushort_t* W2T   = (ushort_t*)(ws + OFF_W2T);
  ushort_t* MT    = (ushort_t*)(ws + OFF_MT);
  ushort_t* XB    = (ushort_t*)(ws + OFF_XB);  // aliases W2T

  hipMemsetAsync(d_ws, 0, 8192, stream);       // control block only
  router_kernel<<<T_TOK / 4, 256, 0, stream>>>(x, wrt, rexp, rwts, zpart, ppart, pcnt);
  prefix_kernel<<<1, 64, 0, stream>>>(pcnt, pbase, sbinf, sbbas, blkt);
  scatter_kernel<<<T_TOK / 256, 256, 0, stream>>>(rexp, rwts, pbase, pcur, ecnt, ids, wtsf);
  transpose_w2_kernel<<<dim3(FF / 64, DD / 64, NE), 256, 0, stream>>>(w2, W2T);
  gemm_mt_kernel<<<dim3(NE, DD / BM, DD / BN), 256, 0, stream>>>(W2T, w1, MT);
  convert_x_kernel<<<(T_TOK * DD) / (8 * 256), 256, 0, stream>>>(x, XB);  // after gemm_mt
  gemm_pair_kernel<<<dim3(SBMAX, DD / BN), 256, 0, stream>>>(XB, MT, sbinf, sbbas, blkt, ids, wtsf, out);
  losses_kernel<<<1, 64, 0, stream>>>(zpart, ppart, ecnt, out + (size_t)T_TOK * DD);
}

// Round 6
// 404.057 us; speedup vs baseline: 1.1382x; 1.0960x over previous
//
#include <hip/hip_runtime.h>
#include <hip/hip_bf16.h>
#include <stdint.h>
#include <stddef.h>

// ---------------------------------------------------------------------------
// MoE MLP. MT_e = (W1_e @ W2_e)^T precomputed; out[tok] = wa*(x@M_ea)+wb*(x@M_eb)
// by unordered expert pair (28 pairs), plain stores.
// R6: COUNTED-vmcnt pipeline (T4) in both GEMMs — raw s_barrier, never drain
// vmcnt to 0 mid-loop. Evidence R0-R5: token GEMM pinned 115-138us across 5
// structures, all pipes ~10%; per-tile full drains (__syncthreads / pack-use
// waits) serialize load latency with compute. Counted waits keep the next
// tile's 8 loads in flight across an entire compute phase (m218: +38-73%).
// Staging/fragment/swizzle formulas identical to R3 (refcheck-proven, 0 bank
// conflicts). LDS 64KB dbuf, __launch_bounds__(256,2).
// ---------------------------------------------------------------------------

typedef unsigned short ushort_t;
typedef __attribute__((ext_vector_type(8))) short short8;
typedef __attribute__((ext_vector_type(4))) float floatx4;

#define T_TOK 8192
#define NE    8
#define DD    1024
#define FF    2048
#define W1ROW (NE * FF)
#define NPAIR 28
#define SBMAX 96

#define BM 128
#define BN 128
#define BK 64

#define PIDX(ea, eb) ((ea) * (15 - (ea)) / 2 + (eb) - (ea) - 1)

typedef const __attribute__((address_space(1))) unsigned int gas_u32;
typedef __attribute__((address_space(3)))       unsigned int las_u32;
#define GLOAD16(gp, lp) \
  __builtin_amdgcn_global_load_lds((gas_u32*)(gp), (las_u32*)(lp), 16, 0, 0)

// counted waits (T4) + raw barrier
#define WAITV8()  asm volatile("s_waitcnt vmcnt(8)" ::: "memory")
#define WAITV20() asm volatile("s_waitcnt vmcnt(20)" ::: "memory")
#define WAITV12() asm volatile("s_waitcnt vmcnt(12)" ::: "memory")
#define WAITV4()  asm volatile("s_waitcnt vmcnt(4)" ::: "memory")
#define WAITV0()  asm volatile("s_waitcnt vmcnt(0)" ::: "memory")
#define WAITL0()  do { asm volatile("s_waitcnt lgkmcnt(0)" ::: "memory"); \
                       __builtin_amdgcn_sched_barrier(0); } while (0)
#define BARRIER() __builtin_amdgcn_s_barrier()

__device__ __forceinline__ unsigned short f2bf(float f) {
  union { float f; unsigned u; } c; c.f = f;
  unsigned r = c.u + 0x7fffu + ((c.u >> 16) & 1u);
  return (unsigned short)(r >> 16);
}
__device__ __forceinline__ unsigned packbf2(float a, float b) {
  unsigned ua = __float_as_uint(a) + 0x8000u;
  unsigned ub = __float_as_uint(b) + 0x8000u;
  return __builtin_amdgcn_perm(ub, ua, 0x07060302);
}

#define MFMA16(a, b, c) __builtin_amdgcn_mfma_f32_16x16x32_bf16((a), (b), (c), 0, 0, 0)

// shared compute step (R3-proven fragment/swizzle formulas)
#define GEMM_COMPUTE(b) do { _Pragma("unroll")                                      \
  for (int s = 0; s < 2; ++s) {                                                     \
    short8 fa[4], fb[4];                                                            \
    _Pragma("unroll")                                                               \
    for (int i = 0; i < 4; ++i) { int r = wr * 64 + i * 16 + mrow;                  \
      fa[i] = *(const short8*)&As[b][r * BK + ((((s << 2) | kq) ^ (r & 7)) << 3)]; }\
    _Pragma("unroll")                                                               \
    for (int j = 0; j < 4; ++j) { int r = wc * 64 + j * 16 + mrow;                  \
      fb[j] = *(const short8*)&Bs[b][r * BK + ((((s << 2) | kq) ^ (r & 7)) << 3)]; }\
    _Pragma("unroll")                                                               \
    for (int i = 0; i < 4; ++i) { _Pragma("unroll")                                 \
      for (int j = 0; j < 4; ++j)                                                   \
        acc[i][j] = MFMA16(fa[i], fb[j], acc[i][j]); } } } while (0)

// ---------------- workspace layout (bytes) ----------------------------------
static const size_t OFF_PCNT  = 0;
static const size_t OFF_PCUR  = 896;
static const size_t OFF_ZPART = 1024;
static const size_t OFF_PPART = 1280;
static const size_t OFF_ECNT  = 3328;
static const size_t OFF_SBINF = 3360;
static const size_t OFF_SBBAS = 3744;
static const size_t OFF_BLKT  = 4128;
static const size_t OFF_PBASE = 4160;
static const size_t OFF_REXP  = 8192;
static const size_t OFF_RWTS  = 40960;
static const size_t OFF_IDS   = 106496;
static const size_t OFF_WTS   = 139264;
static const size_t OFF_W2T   = 1048576;              // 32MB
static const size_t OFF_MT    = OFF_W2T + 33554432;   // 16MB
static const size_t OFF_XB    = OFF_W2T;              // aliases W2T
// total 51,380,224 bytes (unchanged)

// ---------------- 1. router + pair counting ---------------------------------
__global__ __launch_bounds__(256)
void router_kernel(const float* __restrict__ x, const float* __restrict__ wrt,
                   unsigned* __restrict__ rexp, float2* __restrict__ rwts,
                   float* __restrict__ zpart, float* __restrict__ ppart,
                   int* __restrict__ pcnt) {
  int w = threadIdx.x >> 6, ln = threadIdx.x & 63;
  int t = blockIdx.x * 4 + w;
  const float* xr = x + (size_t)t * DD;
  float acc[8] = {0.f, 0.f, 0.f, 0.f, 0.f, 0.f, 0.f, 0.f};
  for (int i = 0; i < 16; ++i) {
    int d = ln + (i << 6);
    float xv = xr[d];
    float4 r0 = *(const float4*)(wrt + (size_t)d * 8);
    float4 r1 = *(const float4*)(wrt + (size_t)d * 8 + 4);
    acc[0] += xv * r0.x;  acc[1] += xv * r0.y;
    acc[2] += xv * r0.z;  acc[3] += xv * r0.w;
    acc[4] += xv * r1.x;  acc[5] += xv * r1.y;
    acc[6] += xv * r1.z;  acc[7] += xv * r1.w;
  }
#pragma unroll
  for (int e = 0; e < 8; ++e) {
#pragma unroll
    for (int off = 32; off > 0; off >>= 1) acc[e] += __shfl_xor(acc[e], off, 64);
  }
  if (ln == 0) {
    float m = acc[0];
#pragma unroll
    for (int e = 1; e < 8; ++e) m = fmaxf(m, acc[e]);
    float p[8], s = 0.f;
#pragma unroll
    for (int e = 0; e < 8; ++e) { p[e] = expf(acc[e] - m); s += p[e]; }
    float z = m + logf(s);
    int e1 = 0; float v1 = acc[0];
#pragma unroll
    for (int e = 1; e < 8; ++e) if (acc[e] > v1) { v1 = acc[e]; e1 = e; }
    int e2 = (e1 == 0) ? 1 : 0; float v2 = acc[e2];
#pragma unroll
    for (int e = 0; e < 8; ++e) if (e != e1 && acc[e] > v2) { v2 = acc[e]; e2 = e; }
    float p1 = p[e1], p2 = p[e2];
    float inv = 1.f / (p1 + p2);
    rexp[t] = (unsigned)e1 | ((unsigned)e2 << 8);
    rwts[t] = make_float2(p1 * inv, p2 * inv);
    int sh = blockIdx.x & 63;
    unsafeAtomicAdd(&zpart[sh], z * z);
    float sinv = 1.f / s;
#pragma unroll
    for (int e = 0; e < 8; ++e) unsafeAtomicAdd(&ppart[sh * 8 + e], p[e] * sinv);
    int ea = (e1 < e2) ? e1 : e2, eb = (e1 < e2) ? e2 : e1;
    atomicAdd(&pcnt[PIDX(ea, eb) * 8 + (blockIdx.x & 7)], 1);
  }
}

// ---------------- 2a. prefix -------------------------------------------------
__global__ void prefix_kernel(const int* __restrict__ pcnt, int* __restrict__ pbase,
                              unsigned* __restrict__ sbinf, unsigned* __restrict__ sbbas,
                              int* __restrict__ blkt) {
  __shared__ int c[NPAIR], tb_[NPAIR], cb_[NPAIR];
  int tid = (int)threadIdx.x;
  if (tid < NPAIR) {
    int s = 0;
#pragma unroll
    for (int g = 0; g < 8; ++g) s += pcnt[tid * 8 + g];
    c[tid] = s;
  }
  __syncthreads();
  if (tid == 0) {
    int tb = 0, bb = 0;
    for (int p = 0; p < NPAIR; ++p) {
      tb_[p] = tb; cb_[p] = bb;
      tb += c[p]; bb += (c[p] + 127) >> 7;
    }
    *blkt = bb;
  }
  __syncthreads();
  if (tid < NPAIR) {
    int p = tid, ea = 0, span = 7;
    while (p >= span) { p -= span; ++ea; --span; }
    int eb = ea + 1 + p;
    int cc = c[tid], base = tb_[tid], b0 = cb_[tid];
    pbase[tid] = base;
    int nb = (cc + 127) >> 7;
    for (int k = 0; k < nb; ++k) {
      int rows = cc - k * 128; if (rows > 128) rows = 128;
      sbinf[b0 + k] = (unsigned)ea | ((unsigned)eb << 8) | ((unsigned)rows << 16);
      sbbas[b0 + k] = (unsigned)(base + k * 128);
    }
  }
}

// ---------------- 2b. scatter ------------------------------------------------
__global__ __launch_bounds__(256)
void scatter_kernel(const unsigned* __restrict__ rexp, const float2* __restrict__ rwts,
                    const int* __restrict__ pbase, int* __restrict__ pcur,
                    int* __restrict__ ecnt, int* __restrict__ ids,
                    float2* __restrict__ wts) {
  __shared__ int lcnt[8];
  if (threadIdx.x < 8) lcnt[threadIdx.x] = 0;
  __syncthreads();
  int t = blockIdx.x * 256 + threadIdx.x;
  unsigned re = rexp[t];
  float2 w = rwts[t];
  int e1 = (int)(re & 0xffu), e2 = (int)((re >> 8) & 0xffu);
  atomicAdd(&lcnt[e1], 1);
  atomicAdd(&lcnt[e2], 1);
  int ea, eb; float wa, wb;
  if (e1 < e2) { ea = e1; eb = e2; wa = w.x; wb = w.y; }
  else         { ea = e2; eb = e1; wa = w.y; wb = w.x; }
  int pid = PIDX(ea, eb);
  int slot = atomicAdd(&pcur[pid], 1);
  int idx = pbase[pid] + slot;
  ids[idx] = t;
  wts[idx] = make_float2(wa, wb);
  __syncthreads();
  if (threadIdx.x < 8) atomicAdd(&ecnt[threadIdx.x], lcnt[threadIdx.x]);
}

// ---------------- 3. W2 -> W2T (bf16 [e][j][f]) ------------------------------
__global__ __launch_bounds__(256)
void transpose_w2_kernel(const float* __restrict__ w2, ushort_t* __restrict__ W2T) {
  __shared__ ushort_t tile[64 * 72];
  int e = blockIdx.z, f0 = blockIdx.x * 64, j0 = blockIdx.y * 64;
  int tid = (int)threadIdx.x;
  int r = tid >> 2, c0 = (tid & 3) * 16;
  const float* src = w2 + ((size_t)(e * FF + f0 + r)) * DD + j0 + c0;
  float4 v0 = *(const float4*)(src);
  float4 v1 = *(const float4*)(src + 4);
  float4 v2 = *(const float4*)(src + 8);
  float4 v3 = *(const float4*)(src + 12);
  uint4 pa = make_uint4(packbf2(v0.x, v0.y), packbf2(v0.z, v0.w),
                        packbf2(v1.x, v1.y), packbf2(v1.z, v1.w));
  uint4 pb = make_uint4(packbf2(v2.x, v2.y), packbf2(v2.z, v2.w),
                        packbf2(v3.x, v3.y), packbf2(v3.z, v3.w));
  *(uint4*)&tile[r * 72 + c0]     = pa;
  *(uint4*)&tile[r * 72 + c0 + 8] = pb;
  __syncthreads();
  int j = tid >> 2, g0 = (tid & 3) * 16;
  ushort_t o[16];
#pragma unroll
  for (int i = 0; i < 16; ++i) o[i] = tile[(g0 + i) * 72 + j];
  ushort_t* dst = W2T + ((size_t)(e * DD + j0 + j)) * FF + f0 + g0;
  *(uint4*)(dst)     = *(uint4*)&o[0];
  *(uint4*)(dst + 8) = *(uint4*)&o[8];
}

// ---------------- 3b. x -> XB (bf16) -----------------------------------------
__global__ __launch_bounds__(256)
void convert_x_kernel(const float* __restrict__ x, ushort_t* __restrict__ XB) {
  size_t i = ((size_t)blockIdx.x * 256 + threadIdx.x) * 8;
  float4 f0 = *(const float4*)(x + i);
  float4 f1 = *(const float4*)(x + i + 4);
  uint4 pk = make_uint4(packbf2(f0.x, f0.y), packbf2(f0.z, f0.w),
                        packbf2(f1.x, f1.y), packbf2(f1.z, f1.w));
  *(uint4*)(XB + i) = pk;
}

// ---------------- 4. gemm_mt: counted-vmcnt pipeline ------------------------
// A = W2T rows via gload_lds (counted); B = w1 fp32 reg-staged 4 tiles deep
// (two NAMED regsets), packed between raw barriers. vmcnt ladder 20/12/4/0
// guarantees A(t+1) landed while A(t+2)+B(t+3)+B(t+4) stay in flight.
__global__ __launch_bounds__(256, 2)
void gemm_mt_kernel(const ushort_t* __restrict__ W2T, const float* __restrict__ w1,
                    ushort_t* __restrict__ MT) {
  int e  = blockIdx.x;
  int m0 = blockIdx.y * BM;
  int n0 = blockIdx.z * BN;
  __shared__ alignas(16) ushort_t As[2][BM * BK];
  __shared__ alignas(16) ushort_t Bs[2][BN * BK];
  const ushort_t* Abase = W2T + (size_t)e * DD * FF;
  int tid = (int)threadIdx.x;
  int w = tid >> 6, ln = tid & 63;
  int wr = w >> 1, wc = w & 1;
  int mrow = ln & 15, kq = ln >> 4;
  const ushort_t* agp[4];
#pragma unroll
  for (int it = 0; it < 4; ++it) {
    int r  = w * 32 + it * 8 + (ln >> 3);
    int cs = (ln & 7) ^ (r & 7);
    agp[it] = Abase + (size_t)(m0 + r) * FF + cs * 8;
  }
  const float* bgp[4];
  int brq[4];
#pragma unroll
  for (int it = 0; it < 4; ++it) {
    int r = it * 32 + (tid >> 3), q = tid & 7;
    bgp[it] = w1 + (size_t)(n0 + r) * W1ROW + e * FF + q * 8;
    brq[it] = r * BK + ((q ^ (r & 7)) << 3);
  }
  float4 rA0[4], rA1[4], rB0[4], rB1[4];   // two named regsets (rule #20)

#define MT_ISSUE_A(tt, b) do { _Pragma("unroll")                         \
  for (int it = 0; it < 4; ++it)                                         \
    GLOAD16(agp[it] + (tt) * BK, &As[b][(w * 32 + it * 8) * BK]); } while (0)
#define MT_LOADB(tt, R0, R1) do { _Pragma("unroll")                      \
  for (int it = 0; it < 4; ++it) {                                       \
    R0[it] = *(const float4*)(bgp[it] + (tt) * BK);                      \
    R1[it] = *(const float4*)(bgp[it] + (tt) * BK + 4); } } while (0)
#define MT_PACK(R0, R1, b) do { _Pragma("unroll")                        \
  for (int it = 0; it < 4; ++it) {                                       \
    uint4 pk = make_uint4(packbf2(R0[it].x, R0[it].y), packbf2(R0[it].z, R0[it].w), \
                          packbf2(R1[it].x, R1[it].y), packbf2(R1[it].z, R1[it].w));\
    *(uint4*)&Bs[b][brq[it]] = pk; } } while (0)

  // prologue: tiles 0,1 staged; B tiles 2,3 in regs/flight
  MT_ISSUE_A(0, 0); MT_LOADB(0, rA0, rA1);
  MT_ISSUE_A(1, 1); MT_LOADB(1, rB0, rB1);
  MT_PACK(rA0, rA1, 0); MT_LOADB(2, rA0, rA1);
  MT_PACK(rB0, rB1, 1); MT_LOADB(3, rB0, rB1);   // pack-wait covers A0,A1,B0,B1
  WAITL0(); BARRIER();

  floatx4 acc[4][4] = {};
#pragma unroll 1
  for (int t = 0; t < 32; t += 2) {
    GEMM_COMPUTE(0);                         // tile t (even, buf 0)
    WAITL0(); BARRIER();                     // all done reading buf 0
    if (t + 2 < 32) {
      MT_ISSUE_A(t + 2, 0);
      MT_PACK(rA0, rA1, 0);                  // B(t+2); compiler-wait is counted
      if (t + 4 < 32) MT_LOADB(t + 4, rA0, rA1);
    }
    if (t <= 26)      { WAITV20(); }         // A(t+1) done; 20 newer ops fly
    else if (t == 28) { WAITV12(); }
    else              { WAITV0();  }         // t == 30: drain A(31)
    WAITL0(); BARRIER();                     // buf-0 writes visible

    GEMM_COMPUTE(1);                         // tile t+1 (odd, buf 1)
    if (t + 1 == 31) break;
    WAITL0(); BARRIER();
    if (t + 3 < 32) {
      MT_ISSUE_A(t + 3, 1);
      MT_PACK(rB0, rB1, 1);                  // B(t+3)
      if (t + 5 < 32) MT_LOADB(t + 5, rB0, rB1);
    }
    if (t + 1 <= 27)      { WAITV20(); }
    else /* t+1 == 29 */  { WAITV4();  }     // only A(31) newer than A(30)
    WAITL0(); BARRIER();
  }
#undef MT_ISSUE_A
#undef MT_LOADB
#undef MT_PACK
  // epilogue: C/D layout col=lane&15, row=(lane>>4)*4+reg
  ushort_t* outp = MT + (size_t)e * DD * DD;
#pragma unroll
  for (int i = 0; i < 4; ++i) {
#pragma unroll
    for (int j = 0; j < 4; ++j) {
#pragma unroll
      for (int rr = 0; rr < 4; ++rr) {
        int m = m0 + wr * 64 + i * 16 + kq * 4 + rr;
        int n = n0 + wc * 64 + j * 16 + mrow;
        outp[(size_t)m * DD + n] = f2bf(acc[i][j][rr]);
      }
    }
  }
}

// ---------------- 5. gemm_pair: counted-vmcnt pipeline -----------------------
// All-gload_lds dbuf. Per tile: compute(b); lgkm0; bar; ISSUE(t+2,b);
// vmcnt(8); bar. Tiles 0-15 expert ea, 16-31 eb (same token rows); single
// accumulator, wa/wb-ratio rescale (preloaded regs) between passes.
__global__ __launch_bounds__(256, 2)
void gemm_pair_kernel(const ushort_t* __restrict__ XB, const ushort_t* __restrict__ MT,
                      const unsigned* __restrict__ sbinf, const unsigned* __restrict__ sbbas,
                      const int* __restrict__ blkt, const int* __restrict__ ids,
                      const float2* __restrict__ wts, float* __restrict__ outp) {
  int lin = blockIdx.x;
  int sb = (lin & 7) * (SBMAX / 8) + (lin >> 3);   // chunked XCD swizzle
  if (sb >= *blkt) return;
  unsigned info = sbinf[sb];
  int tokoff = (int)sbbas[sb];
  int ea = (int)(info & 0xffu), eb = (int)((info >> 8) & 0xffu);
  int rows = (int)((info >> 16) & 0x1ffu);
  int n0 = blockIdx.y * BN;
  __shared__ alignas(16) ushort_t As[2][BM * BK];
  __shared__ alignas(16) ushort_t Bs[2][BN * BK];
  int tid = (int)threadIdx.x;
  int w = tid >> 6, ln = tid & 63;
  int wr = w >> 1, wc = w & 1;
  int mrow = ln & 15, kq = ln >> 4;
  const int* idsE = ids + tokoff;
  const float2* wtsE = wts + tokoff;
  const ushort_t* Ba = MT + (size_t)ea * DD * DD;
  const ushort_t* Bb = MT + (size_t)eb * DD * DD;
  const ushort_t* agp[4];
  size_t bofs[4];
#pragma unroll
  for (int it = 0; it < 4; ++it) {
    int r  = w * 32 + it * 8 + (ln >> 3);
    int cs = (ln & 7) ^ (r & 7);
    int tok = (r < rows) ? idsE[r] : idsE[0];
    agp[it] = XB + (size_t)tok * DD + cs * 8;
    bofs[it] = (size_t)(n0 + r) * DD + cs * 8;
  }
  // preload rescale ratios (no vmem inside the pipelined loop)
  float rat[4][4];
#pragma unroll
  for (int i = 0; i < 4; ++i) {
#pragma unroll
    for (int rr = 0; rr < 4; ++rr) {
      int r2 = wr * 64 + i * 16 + kq * 4 + rr;
      float2 wv = (r2 < rows) ? wtsE[r2] : make_float2(1.f, 1.f);
      rat[i][rr] = wv.x / wv.y;
    }
  }

#define P_ISSUE(tt, b) do {                                                  \
    int ko = ((tt) & 15) * BK;                                               \
    const ushort_t* Bx = ((tt) < 16) ? Ba : Bb;                              \
    _Pragma("unroll")                                                        \
    for (int it = 0; it < 4; ++it)                                           \
      GLOAD16(agp[it] + ko, &As[b][(w * 32 + it * 8) * BK]);                 \
    _Pragma("unroll")                                                        \
    for (int it = 0; it < 4; ++it)                                           \
      GLOAD16(Bx + bofs[it] + ko, &Bs[b][(w * 32 + it * 8) * BK]); } while (0)

  P_ISSUE(0, 0);
  P_ISSUE(1, 1);
  WAITV8(); BARRIER();                       // tile0 landed everywhere

  floatx4 acc[4][4] = {};
#pragma unroll 1
  for (int t = 0; t < 32; ++t) {
    int b = t & 1;
    GEMM_COMPUTE(b);
    if (t == 15) {                           // expert switch: acc *= wa/wb
#pragma unroll
      for (int i = 0; i < 4; ++i)
#pragma unroll
        for (int rr = 0; rr < 4; ++rr)
#pragma unroll
          for (int j = 0; j < 4; ++j)
            acc[i][j][rr] *= rat[i][rr];
    }
    if (t == 31) break;
    WAITL0(); BARRIER();                     // all done reading buf b
    if (t + 2 < 32) { P_ISSUE(t + 2, b); WAITV8(); }   // t+1 landed; t+2 flies
    else            { WAITV0(); }            // t == 30: drain tile 31
    BARRIER();                               // tile t+1 visible to all
  }
#undef P_ISSUE
  // epilogue: plain stores (×wb), each out element written exactly once
#pragma unroll
  for (int i = 0; i < 4; ++i) {
#pragma unroll
    for (int rr = 0; rr < 4; ++rr) {
      int r2 = wr * 64 + i * 16 + kq * 4 + rr;
      if (r2 < rows) {
        int tok = idsE[r2];
        float wb_ = wtsE[r2].y;
        float* orow = outp + (size_t)tok * DD + n0;
#pragma unroll
        for (int j = 0; j < 4; ++j)
          orow[wc * 64 + j * 16 + mrow] = wb_ * acc[i][j][rr];
      }
    }
  }
}

// ---------------- 6. losses + f_i (wave-parallel) ----------------------------
__global__ void losses_kernel(const float* __restrict__ zpart, const float* __restrict__ ppart,
                              const int* __restrict__ ecnt, float* __restrict__ outaux) {
  int ln = threadIdx.x & 63;
  float z = zpart[ln];
  float p8[8];
#pragma unroll
  for (int e = 0; e < 8; ++e) p8[e] = ppart[ln * 8 + e];
#pragma unroll
  for (int off = 32; off > 0; off >>= 1) {
    z += __shfl_xor(z, off, 64);
#pragma unroll
    for (int e = 0; e < 8; ++e) p8[e] += __shfl_xor(p8[e], off, 64);
  }
  if (ln == 0) {
    float lb = 0.f;
#pragma unroll
    for (int e = 0; e < 8; ++e) {
      float fi = (float)ecnt[e] / (float)(T_TOK * 2);
      lb += fi * (p8[e] / (float)T_TOK);
      outaux[2 + e] = fi;
    }
    outaux[0] = z / (float)T_TOK;
    outaux[1] = lb * (float)NE;
  }
}

// ---------------- launch -----------------------------------------------------
extern "C" void kernel_launch(void* const* d_in, const int* in_sizes, int n_in,
                              void* d_out, int out_size, void* d_ws, size_t ws_size,
                              hipStream_t stream) {
  const float* x   = (const float*)d_in[0];
  const float* wrt = (const float*)d_in[1];
  const float* w1  = (const float*)d_in[2];
  const float* w2  = (const float*)d_in[3];
  float* out = (float*)d_out;

  char* ws = (char*)d_ws;
  int*      pcnt  = (int*)     (ws + OFF_PCNT);
  int*      pcur  = (int*)     (ws + OFF_PCUR);
  float*    zpart = (float*)   (ws + OFF_ZPART);
  float*    ppart = (float*)   (ws + OFF_PPART);
  int*      ecnt  = (int*)     (ws + OFF_ECNT);
  unsigned* sbinf = (unsigned*)(ws + OFF_SBINF);
  unsigned* sbbas = (unsigned*)(ws + OFF_SBBAS);
  int*      blkt  = (int*)     (ws + OFF_BLKT);
  int*      pbase = (int*)     (ws + OFF_PBASE);
  unsigned* rexp  = (unsigned*)(ws + OFF_REXP);
  float2*   rwts  = (float2*)  (ws + OFF_RWTS);
  int*      ids   = (int*)     (ws + OFF_IDS);
  float2*   wtsf  = (float2*)  (ws + OFF_WTS);
  ushort_t* W2T   = (ushort_t*)(ws + OFF_W2T);
  ushort_t* MT    = (ushort_t*)(ws + OFF_MT);
  ushort_t* XB    = (ushort_t*)(ws + OFF_XB);

  hipMemsetAsync(d_ws, 0, 8192, stream);
  router_kernel<<<T_TOK / 4, 256, 0, stream>>>(x, wrt, rexp, rwts, zpart, ppart, pcnt);
  prefix_kernel<<<1, 64, 0, stream>>>(pcnt, pbase, sbinf, sbbas, blkt);
  scatter_kernel<<<T_TOK / 256, 256, 0, stream>>>(rexp, rwts, pbase, pcur, ecnt, ids, wtsf);
  transpose_w2_kernel<<<dim3(FF / 64, DD / 64, NE), 256, 0, stream>>>(w2, W2T);
  gemm_mt_kernel<<<dim3(NE, DD / BM, DD / BN), 256, 0, stream>>>(W2T, w1, MT);
  convert_x_kernel<<<(T_TOK * DD) / (8 * 256), 256, 0, stream>>>(x, XB);
  gemm_pair_kernel<<<dim3(SBMAX, DD / BN), 256, 0, stream>>>(XB, MT, sbinf, sbbas, blkt, ids, wtsf, out);
  losses_kernel<<<1, 64, 0, stream>>>(zpart, ppart, ecnt, out + (size_t)T_TOK * DD);
}